// Round 1
// baseline (377.492 us; speedup 1.0000x reference)
//
#include <hip/hip_runtime.h>
#include <hip/hip_bf16.h>

#define EMBED 768
#define HEADS 12
#define DHEAD 64
#define TOKENS 32768          // B*S = 32*1024
#define QKVN  (3*EMBED)       // 2304
#define QK_SCALE 0.03608439182435161f  // 768^-0.5

typedef __attribute__((ext_vector_type(8))) __bf16 bf16x8;
typedef __attribute__((ext_vector_type(4))) __bf16 bf16x4;
typedef __attribute__((ext_vector_type(4))) float  f32x4;

__device__ __forceinline__ void gload_lds16(const void* gptr, void* lptr) {
    __builtin_amdgcn_global_load_lds(
        (const __attribute__((address_space(1))) void*)gptr,
        (__attribute__((address_space(3))) void*)lptr,
        16, 0, 0);
}

// ---------------- f32 -> bf16 cast (vectorized) ----------------
__global__ __launch_bounds__(256) void k_cvt_bf16(const float4* __restrict__ src,
                                                  bf16x4* __restrict__ dst, int n4) {
    int i = blockIdx.x * blockDim.x + threadIdx.x;
    int stride = gridDim.x * blockDim.x;
    for (; i < n4; i += stride) {
        float4 f = src[i];
        bf16x4 o;
        o[0] = (__bf16)f.x; o[1] = (__bf16)f.y; o[2] = (__bf16)f.z; o[3] = (__bf16)f.w;
        dst[i] = o;
    }
}

// ---------------- transpose + cast: src [R][C] f32 -> dst [C][R] bf16 ----------------
__global__ __launch_bounds__(256) void k_transpose_cvt(const float* __restrict__ src,
                                                       __bf16* __restrict__ dst,
                                                       int R, int C) {
    __shared__ float tile[32][33];
    int c0 = blockIdx.x * 32, r0 = blockIdx.y * 32;
    int tx = threadIdx.x, ty = threadIdx.y;   // 32 x 8
#pragma unroll
    for (int j = 0; j < 4; j++) {
        int r = r0 + ty + j * 8;
        tile[ty + j * 8][tx] = src[(long)r * C + c0 + tx];
    }
    __syncthreads();
#pragma unroll
    for (int j = 0; j < 4; j++) {
        int c = c0 + ty + j * 8;
        dst[(long)c * R + r0 + tx] = (__bf16)tile[tx][ty + j * 8];
    }
}

// ---------------- bf16 MFMA GEMM: C[M][N] = A[M][K] @ Bt[N][K]^T + bias ----------------
// 128x128 tile, BK=32, 256 threads (4 waves, 2x2 of 64x64), m97 structure.
template <typename OutT>
__global__ __launch_bounds__(256) void gemm_bt(const __bf16* __restrict__ A,
                                               const __bf16* __restrict__ Bt,
                                               const float* __restrict__ bias,
                                               OutT* __restrict__ C,
                                               int M, int N, int K) {
    __shared__ __bf16 As[128 * 32];
    __shared__ __bf16 Bs[128 * 32];
    const int t = threadIdx.x;
    const int w = t >> 6, lane = t & 63;
    const int ntn = N >> 7;
    const int brow = blockIdx.x / ntn, bcol = blockIdx.x % ntn;
    const int wr = w >> 1, wc = w & 1;

    f32x4 acc[4][4] = {};

    const long arow0 = (long)brow * 128;
    const long bcol0 = (long)bcol * 128;
    const int nk = K >> 5;

    // stage tile kt=0
    {
        const int k0 = 0;
#pragma unroll
        for (int i = 0; i < 2; i++) {
            int c = i * 256 + w * 64 + lane;
            int r = c >> 2, e8 = (c & 3) * 8;
            gload_lds16(A + (arow0 + r) * K + k0 + e8, (void*)&As[(size_t)(i * 256 + w * 64) * 8]);
            gload_lds16(Bt + (bcol0 + r) * K + k0 + e8, (void*)&Bs[(size_t)(i * 256 + w * 64) * 8]);
        }
    }

    const int k0f   = (lane >> 4) * 8;
    const int rbase = wr * 64 + (lane & 15);
    const int cbase = wc * 64 + (lane & 15);

    for (int kt = 0;; kt++) {
        __syncthreads();   // staging done (compiler drains vmcnt before s_barrier)
        bf16x8 af[4], bf[4];
#pragma unroll
        for (int m = 0; m < 4; m++) af[m] = *(const bf16x8*)&As[(rbase + m * 16) * 32 + k0f];
#pragma unroll
        for (int n = 0; n < 4; n++) bf[n] = *(const bf16x8*)&Bs[(cbase + n * 16) * 32 + k0f];
#pragma unroll
        for (int m = 0; m < 4; m++)
#pragma unroll
            for (int n = 0; n < 4; n++)
                acc[m][n] = __builtin_amdgcn_mfma_f32_16x16x32_bf16(af[m], bf[n], acc[m][n], 0, 0, 0);
        if (kt + 1 == nk) break;
        __syncthreads();   // compute done, safe to overwrite LDS
        const int k0 = (kt + 1) * 32;
#pragma unroll
        for (int i = 0; i < 2; i++) {
            int c = i * 256 + w * 64 + lane;
            int r = c >> 2, e8 = (c & 3) * 8;
            gload_lds16(A + (arow0 + r) * K + k0 + e8, (void*)&As[(size_t)(i * 256 + w * 64) * 8]);
            gload_lds16(Bt + (bcol0 + r) * K + k0 + e8, (void*)&Bs[(size_t)(i * 256 + w * 64) * 8]);
        }
    }

    // epilogue: C/D layout col=lane&15, row=(lane>>4)*4+j  [m89/m91 verified]
    const int colb = (int)bcol0 + wc * 64 + (lane & 15);
    const int rowb = (int)arow0 + wr * 64 + ((lane >> 4) * 4);
#pragma unroll
    for (int n = 0; n < 4; n++) {
        int col = colb + n * 16;
        float bv = bias[col];
#pragma unroll
        for (int m = 0; m < 4; m++) {
            int row = rowb + m * 16;
#pragma unroll
            for (int j = 0; j < 4; j++) {
                float v = acc[m][n][j] + bv;
                C[(long)(row + j) * N + col] = (OutT)v;
            }
        }
    }
}

// ---------------- per-token 12x12 head attention ----------------
// qkv row layout: [h*192 + {0..63:q, 64..127:k, 128..191:v}]
__global__ __launch_bounds__(256) void k_attn(const __bf16* __restrict__ qkv,
                                              __bf16* __restrict__ out) {
    __shared__ float rows[4][QKVN];
    __shared__ float wts[4][144];
    const int w = threadIdx.x >> 6, lane = threadIdx.x & 63;
    const long token = (long)blockIdx.x * 4 + w;
    const __bf16* rp = qkv + token * QKVN;
    float* row = rows[w];
    float* wt  = wts[w];

    // stage row to LDS as f32
#pragma unroll
    for (int i = 0; i < 9; i++) {
        int c = i * 64 + lane;               // chunk of 4 elems, 576 chunks
        bf16x4 v = *(const bf16x4*)(rp + (size_t)c * 4);
        float4 f = make_float4((float)v[0], (float)v[1], (float)v[2], (float)v[3]);
        *(float4*)(row + c * 4) = f;
    }
    __syncthreads();

    // scores[h][g] = q_h . k_g * scale   (144 dots of 64)
    for (int p = lane; p < 144; p += 64) {
        int h = p / 12, g = p - h * 12;
        const float* qp = row + h * 192;
        const float* kp = row + g * 192 + 64;
        float s = 0.f;
#pragma unroll
        for (int d = 0; d < 64; d += 4) {
            float4 qv = *(const float4*)(qp + d);
            float4 kv = *(const float4*)(kp + d);
            s += qv.x * kv.x + qv.y * kv.y + qv.z * kv.z + qv.w * kv.w;
        }
        wt[p] = s * QK_SCALE;
    }
    __syncthreads();

    // softmax per row h (12 lanes)
    if (lane < 12) {
        float s[12];
#pragma unroll
        for (int g = 0; g < 12; g++) s[g] = wt[lane * 12 + g];
        float m = s[0];
#pragma unroll
        for (int g = 1; g < 12; g++) m = fmaxf(m, s[g]);
        float sum = 0.f;
#pragma unroll
        for (int g = 0; g < 12; g++) { s[g] = __expf(s[g] - m); sum += s[g]; }
        float inv = 1.0f / sum;
#pragma unroll
        for (int g = 0; g < 12; g++) wt[lane * 12 + g] = s[g] * inv;
    }
    __syncthreads();

    // out[h][d] = sum_g wt[h][g] * v[g][d];  out flat index h*64+d
#pragma unroll
    for (int h = 0; h < 12; h++) {
        float a = 0.f;
#pragma unroll
        for (int g = 0; g < 12; g++) a += wt[h * 12 + g] * row[g * 192 + 128 + lane];
        out[token * EMBED + h * 64 + lane] = (__bf16)a;
    }
}

extern "C" void kernel_launch(void* const* d_in, const int* in_sizes, int n_in,
                              void* d_out, int out_size, void* d_ws, size_t ws_size,
                              hipStream_t stream) {
    const float* x     = (const float*)d_in[0];
    const float* w_qkv = (const float*)d_in[1];
    const float* b_qkv = (const float*)d_in[2];
    const float* w_o   = (const float*)d_in[3];
    const float* b_o   = (const float*)d_in[4];
    float* out = (float*)d_out;

    char* ws = (char*)d_ws;
    size_t off = 0;
    auto take = [&](size_t bytes) {
        char* p = ws + off;
        off += (bytes + 255) & ~(size_t)255;
        return p;
    };
    __bf16* wqkvt = (__bf16*)take((size_t)QKVN * EMBED * 2);
    __bf16* wot   = (__bf16*)take((size_t)EMBED * EMBED * 2);
    __bf16* xb    = (__bf16*)take((size_t)TOKENS * EMBED * 2);
    __bf16* qkvb  = (__bf16*)take((size_t)TOKENS * QKVN * 2);
    __bf16* attno = xb;  // x_bf16 dead after GEMM1; reuse

    // x -> bf16
    int n4 = TOKENS * EMBED / 4;
    k_cvt_bf16<<<2048, 256, 0, stream>>>((const float4*)x, (bf16x4*)xb, n4);

    // weight transposes [K][N] f32 -> [N][K] bf16
    dim3 tb(32, 8);
    k_transpose_cvt<<<dim3(QKVN / 32, EMBED / 32), tb, 0, stream>>>(w_qkv, wqkvt, EMBED, QKVN);
    k_transpose_cvt<<<dim3(EMBED / 32, EMBED / 32), tb, 0, stream>>>(w_o, wot, EMBED, EMBED);

    // GEMM1: qkv = x @ w_qkv + b_qkv   -> bf16
    gemm_bt<__bf16><<<(TOKENS / 128) * (QKVN / 128), 256, 0, stream>>>(
        xb, wqkvt, b_qkv, qkvb, TOKENS, QKVN, EMBED);

    // per-token head-attention -> bf16
    k_attn<<<TOKENS / 4, 256, 0, stream>>>(qkvb, attno);

    // GEMM2: out = attn_out @ w_o + b_o  -> f32
    gemm_bt<float><<<(TOKENS / 128) * (EMBED / 128), 256, 0, stream>>>(
        attno, wot, b_o, out, TOKENS, EMBED, EMBED);
}

// Round 2
// 346.066 us; speedup vs baseline: 1.0908x; 1.0908x over previous
//
#include <hip/hip_runtime.h>
#include <hip/hip_bf16.h>

#define EMBED 768
#define HEADS 12
#define TOKENS 32768          // B*S = 32*1024
#define QKVN  (3*EMBED)       // 2304
#define KDIM  768
#define QK_SCALE 0.03608439182435161f  // 768^-0.5

typedef __attribute__((ext_vector_type(8))) __bf16 bf16x8;
typedef __attribute__((ext_vector_type(4))) __bf16 bf16x4;
typedef __attribute__((ext_vector_type(4))) float  f32x4;

__device__ __forceinline__ void gload_lds16(const void* gptr, void* lptr) {
    __builtin_amdgcn_global_load_lds(
        (const __attribute__((address_space(1))) void*)gptr,
        (__attribute__((address_space(3))) void*)lptr,
        16, 0, 0);
}

// ---------------- f32 -> bf16 cast (vectorized) ----------------
__global__ __launch_bounds__(256) void k_cvt_bf16(const float4* __restrict__ src,
                                                  bf16x4* __restrict__ dst, int n4) {
    int i = blockIdx.x * blockDim.x + threadIdx.x;
    int stride = gridDim.x * blockDim.x;
    for (; i < n4; i += stride) {
        float4 f = src[i];
        bf16x4 o;
        o[0] = (__bf16)f.x; o[1] = (__bf16)f.y; o[2] = (__bf16)f.z; o[3] = (__bf16)f.w;
        dst[i] = o;
    }
}

// ---------------- transpose + cast: src [R][C] f32 -> dst [C][R] bf16 ----------------
__global__ __launch_bounds__(256) void k_transpose_cvt(const float* __restrict__ src,
                                                       __bf16* __restrict__ dst,
                                                       int R, int C) {
    __shared__ float tile[32][33];
    int c0 = blockIdx.x * 32, r0 = blockIdx.y * 32;
    int tx = threadIdx.x, ty = threadIdx.y;   // 32 x 8
#pragma unroll
    for (int j = 0; j < 4; j++) {
        int r = r0 + ty + j * 8;
        tile[ty + j * 8][tx] = src[(long)r * C + c0 + tx];
    }
    __syncthreads();
#pragma unroll
    for (int j = 0; j < 4; j++) {
        int c = c0 + ty + j * 8;
        dst[(long)c * R + r0 + tx] = (__bf16)tile[tx][ty + j * 8];
    }
}

// ================= 256x256 8-phase bf16 MFMA GEMM (K=768) =================
// C[M][N] = A[M][K] @ Bt[N][K]^T + bias.  512 thr = 8 waves (2M x 4N),
// 16-row/col interleaved frags.  LDS 128KB: A[2buf][2 mhalf][128][64] swz
// (byte ^= (r&7)<<4), B[2buf][2 khalf][256][32] swz (kb16 ^= (r>>1)&3).
// Phases per K-tile: (mq0,kh0)(mq0,kh1)(mq1,kh0)(mq1,kh1).
// Stage slots: ph1 1.Ah1(t+1) | ph2 1.Bk1(t+1) | ph3 0.Ah0(t+2) |
// ph4 0.Bk0(t+2) +vmcnt(4) | ph5 0.Bk1(t+2) | ph6 0.Ah1(t+2) |
// ph7 1.Ah0(t+3) | ph8 1.Bk0(t+3) +vmcnt(4).   (ledger-verified)
template <typename OutT>
__global__ __launch_bounds__(512, 2) void gemm8(const __bf16* __restrict__ A,
                                                const __bf16* __restrict__ Bt,
                                                const float* __restrict__ bias,
                                                OutT* __restrict__ C, int N) {
    extern __shared__ char lds[];
    const int tid = threadIdx.x;
    const int w = tid >> 6, lane = tid & 63;
    const int wr = w >> 2, wc = w & 3;
    const int l15 = lane & 15, l16 = lane >> 4;
    const int K = KDIM;

    // XCD-aware block swizzle (nwg % 8 == 0 for both our grids)
    const int nbx = N >> 8;
    const int nwg = gridDim.x;
    const int cpx = nwg >> 3;
    const int bid = blockIdx.x;
    const int swz = (bid & 7) * cpx + (bid >> 3);
    const int brow = swz / nbx, bcol = swz % nbx;
    const long arow0 = (long)brow * 256;
    const long ncol0 = (long)bcol * 256;

#define AOFF(b, mh) (((b) * 2 + (mh)) * 16384)
#define BOFF(b, kh) (65536 + ((b) * 2 + (kh)) * 16384)

    // ---- staging precompute (pre-swizzled global source, linear LDS dest) ----
    const int rA0 = tid >> 3;                                  // 0..63
    const int cbA = ((tid & 7) * 16) ^ ((rA0 & 7) << 4);       // byte col in A row
    const int rB0 = tid >> 2;                                  // 0..127
    const int kbB = (((tid & 3) ^ ((tid >> 3) & 3)) * 16);     // byte col in B khalf row
    const int ldsw = w * 1024;                                 // wave slice

    auto stageA = [&](int b, int mh, int kt) {
#pragma unroll
        for (int j = 0; j < 2; ++j) {
            const __bf16* g = A + (arow0 + mh * 128 + j * 64 + rA0) * K + kt * 64 + (cbA >> 1);
            gload_lds16(g, lds + AOFF(b, mh) + j * 8192 + ldsw);
        }
    };
    auto stageB = [&](int b, int kh, int kt) {
#pragma unroll
        for (int j = 0; j < 2; ++j) {
            const __bf16* g = Bt + (ncol0 + j * 128 + rB0) * K + kt * 64 + kh * 32 + (kbB >> 1);
            gload_lds16(g, lds + BOFF(b, kh) + j * 8192 + ldsw);
        }
    };

    // ---- fragment-read precompute (byte offsets, swizzled) ----
    const int xorv = (lane & 7) << 4;
    const int arow_part = (wr * 16 + l15) * 128;
    const int aco0 = arow_part + ((l16 * 16) ^ xorv);          // kh=0
    const int aco1 = arow_part + ((64 + l16 * 16) ^ xorv);     // kh=1
    const int bco = (wc * 16 + l15) * 64 + ((l16 ^ ((l15 >> 1) & 3)) * 16);

    f32x4 acc[8][4] = {};

#define PHASE(bb, mq, kh, STAGE, WAIT) { \
    bf16x8 af[4], bfr[4]; \
    _Pragma("unroll") for (int f = 0; f < 4; ++f) \
        af[f] = *(const bf16x8*)(lds + AOFF(bb, mq) + f * 4096 + ((kh) ? aco1 : aco0)); \
    _Pragma("unroll") for (int g = 0; g < 4; ++g) \
        bfr[g] = *(const bf16x8*)(lds + BOFF(bb, kh) + g * 4096 + bco); \
    STAGE; \
    __builtin_amdgcn_s_barrier(); \
    asm volatile("s_waitcnt lgkmcnt(0)" ::: "memory"); \
    __builtin_amdgcn_sched_barrier(0); \
    __builtin_amdgcn_s_setprio(1); \
    _Pragma("unroll") for (int f = 0; f < 4; ++f) \
        _Pragma("unroll") for (int g = 0; g < 4; ++g) \
            acc[(mq) * 4 + f][g] = __builtin_amdgcn_mfma_f32_16x16x32_bf16(af[f], bfr[g], acc[(mq) * 4 + f][g], 0, 0, 0); \
    __builtin_amdgcn_s_setprio(0); \
    WAIT; \
    __builtin_amdgcn_s_barrier(); \
    __builtin_amdgcn_sched_barrier(0); \
}

    // ---- prologue: tile0 (4 halves) + 1.Ah0, 1.Bk0; leave last 2 in flight ----
    stageA(0, 0, 0); stageB(0, 0, 0); stageB(0, 1, 0); stageA(0, 1, 0);
    stageA(1, 0, 1); stageB(1, 0, 1);
    asm volatile("s_waitcnt vmcnt(4)" ::: "memory");
    __builtin_amdgcn_s_barrier();
    __builtin_amdgcn_sched_barrier(0);

    // ---- main loop: iterations 0..4, tiles (2i, 2i+1), stage up to tile 2i+3 ----
    for (int i = 0; i < 5; ++i) {
        const int t = 2 * i;
        PHASE(0, 0, 0, stageA(1, 1, t + 1), );
        PHASE(0, 0, 1, stageB(1, 1, t + 1), );
        PHASE(0, 1, 0, stageA(0, 0, t + 2), );
        PHASE(0, 1, 1, stageB(0, 0, t + 2), asm volatile("s_waitcnt vmcnt(4)" ::: "memory"));
        PHASE(1, 0, 0, stageB(0, 1, t + 2), );
        PHASE(1, 0, 1, stageA(0, 1, t + 2), );
        PHASE(1, 1, 0, stageA(1, 0, t + 3), );
        PHASE(1, 1, 1, stageB(1, 0, t + 3), asm volatile("s_waitcnt vmcnt(4)" ::: "memory"));
    }
    // ---- epilogue iteration: tiles 10, 11; drain ----
    PHASE(0, 0, 0, stageA(1, 1, 11), );
    PHASE(0, 0, 1, stageB(1, 1, 11), );
    PHASE(0, 1, 0, , );
    PHASE(0, 1, 1, , asm volatile("s_waitcnt vmcnt(0)" ::: "memory"));
    PHASE(1, 0, 0, , );
    PHASE(1, 0, 1, , );
    PHASE(1, 1, 0, , );
    PHASE(1, 1, 1, , );
#undef PHASE
#undef AOFF
#undef BOFF

    // ---- C write: row = arow0 + mf*32 + wr*16 + l16*4 + j, col = ncol0 + g*64 + wc*16 + l15
#pragma unroll
    for (int mf = 0; mf < 8; ++mf) {
        const int row = (int)arow0 + mf * 32 + wr * 16 + l16 * 4;
#pragma unroll
        for (int g = 0; g < 4; ++g) {
            const int col = (int)ncol0 + g * 64 + wc * 16 + l15;
            const float bv = bias[col];
#pragma unroll
            for (int j = 0; j < 4; ++j) {
                C[(long)(row + j) * N + col] = (OutT)(acc[mf][g][j] + bv);
            }
        }
    }
}

// ---------------- per-token 12x12 head attention ----------------
// qkv row layout: [h*192 + {0..63:q, 64..127:k, 128..191:v}]
__global__ __launch_bounds__(256) void k_attn(const __bf16* __restrict__ qkv,
                                              __bf16* __restrict__ out) {
    __shared__ float rows[4][QKVN];
    __shared__ float wts[4][144];
    const int w = threadIdx.x >> 6, lane = threadIdx.x & 63;
    const long token = (long)blockIdx.x * 4 + w;
    const __bf16* rp = qkv + token * QKVN;
    float* row = rows[w];
    float* wt  = wts[w];

#pragma unroll
    for (int i = 0; i < 9; i++) {
        int c = i * 64 + lane;
        bf16x4 v = *(const bf16x4*)(rp + (size_t)c * 4);
        float4 f = make_float4((float)v[0], (float)v[1], (float)v[2], (float)v[3]);
        *(float4*)(row + c * 4) = f;
    }
    __syncthreads();

    for (int p = lane; p < 144; p += 64) {
        int h = p / 12, g = p - h * 12;
        const float* qp = row + h * 192;
        const float* kp = row + g * 192 + 64;
        float s = 0.f;
#pragma unroll
        for (int d = 0; d < 64; d += 4) {
            float4 qv = *(const float4*)(qp + d);
            float4 kv = *(const float4*)(kp + d);
            s += qv.x * kv.x + qv.y * kv.y + qv.z * kv.z + qv.w * kv.w;
        }
        wt[p] = s * QK_SCALE;
    }
    __syncthreads();

    if (lane < 12) {
        float s[12];
#pragma unroll
        for (int g = 0; g < 12; g++) s[g] = wt[lane * 12 + g];
        float m = s[0];
#pragma unroll
        for (int g = 1; g < 12; g++) m = fmaxf(m, s[g]);
        float sum = 0.f;
#pragma unroll
        for (int g = 0; g < 12; g++) { s[g] = __expf(s[g] - m); sum += s[g]; }
        float inv = 1.0f / sum;
#pragma unroll
        for (int g = 0; g < 12; g++) wt[lane * 12 + g] = s[g] * inv;
    }
    __syncthreads();

#pragma unroll
    for (int h = 0; h < 12; h++) {
        float a = 0.f;
#pragma unroll
        for (int g = 0; g < 12; g++) a += wt[h * 12 + g] * row[g * 192 + 128 + lane];
        out[token * EMBED + h * 64 + lane] = (__bf16)a;
    }
}

extern "C" void kernel_launch(void* const* d_in, const int* in_sizes, int n_in,
                              void* d_out, int out_size, void* d_ws, size_t ws_size,
                              hipStream_t stream) {
    const float* x     = (const float*)d_in[0];
    const float* w_qkv = (const float*)d_in[1];
    const float* b_qkv = (const float*)d_in[2];
    const float* w_o   = (const float*)d_in[3];
    const float* b_o   = (const float*)d_in[4];
    float* out = (float*)d_out;

    char* ws = (char*)d_ws;
    size_t off = 0;
    auto take = [&](size_t bytes) {
        char* p = ws + off;
        off += (bytes + 255) & ~(size_t)255;
        return p;
    };
    __bf16* wqkvt = (__bf16*)take((size_t)QKVN * EMBED * 2);
    __bf16* wot   = (__bf16*)take((size_t)EMBED * EMBED * 2);
    __bf16* xb    = (__bf16*)take((size_t)TOKENS * EMBED * 2);
    __bf16* qkvb  = (__bf16*)take((size_t)TOKENS * QKVN * 2);
    __bf16* attno = xb;  // x_bf16 dead after GEMM1; reuse

    // allow 128KB dynamic LDS (no-op if already permitted)
    static bool attr_done = false;
    if (!attr_done) {
        hipFuncSetAttribute((const void*)gemm8<__bf16>,
                            hipFuncAttributeMaxDynamicSharedMemorySize, 131072);
        hipFuncSetAttribute((const void*)gemm8<float>,
                            hipFuncAttributeMaxDynamicSharedMemorySize, 131072);
        attr_done = true;
    }

    int n4 = TOKENS * EMBED / 4;
    k_cvt_bf16<<<2048, 256, 0, stream>>>((const float4*)x, (bf16x4*)xb, n4);

    dim3 tb(32, 8);
    k_transpose_cvt<<<dim3(QKVN / 32, EMBED / 32), tb, 0, stream>>>(w_qkv, wqkvt, EMBED, QKVN);
    k_transpose_cvt<<<dim3(EMBED / 32, EMBED / 32), tb, 0, stream>>>(w_o, wot, EMBED, EMBED);

    // GEMM1: qkv = x @ w_qkv + b_qkv   -> bf16  (1152 wg, %8==0)
    gemm8<__bf16><<<(TOKENS / 256) * (QKVN / 256), 512, 131072, stream>>>(
        xb, wqkvt, b_qkv, qkvb, QKVN);

    k_attn<<<TOKENS / 4, 256, 0, stream>>>(qkvb, attno);

    // GEMM2: out = attn_out @ w_o + b_o  -> f32  (384 wg, %8==0)
    gemm8<float><<<(TOKENS / 256) * (EMBED / 256), 512, 131072, stream>>>(
        attno, wot, b_o, out, EMBED);
}

// Round 3
// 274.457 us; speedup vs baseline: 1.3754x; 1.2609x over previous
//
#include <hip/hip_runtime.h>
#include <hip/hip_bf16.h>

#define EMBED 768
#define HEADS 12
#define TOKENS 32768          // B*S = 32*1024
#define QKVN  (3*EMBED)       // 2304
#define KDIM  768
#define QK_SCALE 0.03608439182435161f  // 768^-0.5

typedef __attribute__((ext_vector_type(8))) __bf16 bf16x8;
typedef __attribute__((ext_vector_type(4))) __bf16 bf16x4;
typedef __attribute__((ext_vector_type(4))) float  f32x4;

__device__ __forceinline__ void gload_lds16(const void* gptr, void* lptr) {
    __builtin_amdgcn_global_load_lds(
        (const __attribute__((address_space(1))) void*)gptr,
        (__attribute__((address_space(3))) void*)lptr,
        16, 0, 0);
}

// ---------------- f32 -> bf16 cast (vectorized) ----------------
__global__ __launch_bounds__(256) void k_cvt_bf16(const float4* __restrict__ src,
                                                  bf16x4* __restrict__ dst, int n4) {
    int i = blockIdx.x * blockDim.x + threadIdx.x;
    int stride = gridDim.x * blockDim.x;
    for (; i < n4; i += stride) {
        float4 f = src[i];
        bf16x4 o;
        o[0] = (__bf16)f.x; o[1] = (__bf16)f.y; o[2] = (__bf16)f.z; o[3] = (__bf16)f.w;
        dst[i] = o;
    }
}

// ---------------- transpose + cast: src [R][C] f32 -> dst [C][R] bf16 ----------------
__global__ __launch_bounds__(256) void k_transpose_cvt(const float* __restrict__ src,
                                                       __bf16* __restrict__ dst,
                                                       int R, int C) {
    __shared__ float tile[32][33];
    int c0 = blockIdx.x * 32, r0 = blockIdx.y * 32;
    int tx = threadIdx.x, ty = threadIdx.y;   // 32 x 8
#pragma unroll
    for (int j = 0; j < 4; j++) {
        int r = r0 + ty + j * 8;
        tile[ty + j * 8][tx] = src[(long)r * C + c0 + tx];
    }
    __syncthreads();
#pragma unroll
    for (int j = 0; j < 4; j++) {
        int c = c0 + ty + j * 8;
        dst[(long)c * R + r0 + tx] = (__bf16)tile[tx][ty + j * 8];
    }
}

// ================= 256x256 8-phase bf16 MFMA GEMM (K=768) =================
// Phase order per K-tile: (mq0,kh0)(mq1,kh0)(mq0,kh1)(mq1,kh1) with B-frags
// register-cached across each mq pair (-25% LDS reads vs re-reading B).
// Stage slots (ledger-verified, steady state, buf0=tile t, buf1=tile t+1):
//  ph1 1.Bk1(t+1) | ph2 1.Ah1(t+1) | ph3 0.Bk0(t+2) | ph4 0.Ah0(t+2)+vmcnt(4)
//  ph5 0.Ah1(t+2) | ph6 0.Bk1(t+2) | ph7 1.Bk0(t+3) | ph8 1.Ah0(t+3)+vmcnt(4)
template <typename OutT>
__global__ __launch_bounds__(512, 2) void gemm8(const __bf16* __restrict__ A,
                                                const __bf16* __restrict__ Bt,
                                                const float* __restrict__ bias,
                                                OutT* __restrict__ C, int N) {
    extern __shared__ char lds[];
    const int tid = threadIdx.x;
    const int w = tid >> 6, lane = tid & 63;
    const int wr = w >> 2, wc = w & 3;
    const int l15 = lane & 15, l16 = lane >> 4;
    const int K = KDIM;

    // XCD-aware block swizzle (nwg % 8 == 0 for both our grids)
    const int nbx = N >> 8;
    const int nwg = gridDim.x;
    const int cpx = nwg >> 3;
    const int bid = blockIdx.x;
    const int swz = (bid & 7) * cpx + (bid >> 3);
    const int brow = swz / nbx, bcol = swz % nbx;
    const long arow0 = (long)brow * 256;
    const long ncol0 = (long)bcol * 256;

#define AOFF(b, mh) (((b) * 2 + (mh)) * 16384)
#define BOFF(b, kh) (65536 + ((b) * 2 + (kh)) * 16384)

    // ---- staging precompute (pre-swizzled global source, linear LDS dest) ----
    const int rA0 = tid >> 3;                                  // 0..63
    const int cbA = ((tid & 7) * 16) ^ ((rA0 & 7) << 4);       // byte col in A row
    const int rB0 = tid >> 2;                                  // 0..127
    const int kbB = (((tid & 3) ^ ((tid >> 3) & 3)) * 16);     // byte col in B khalf row
    const int ldsw = w * 1024;                                 // wave slice

    auto stageA = [&](int b, int mh, int kt) {
#pragma unroll
        for (int j = 0; j < 2; ++j) {
            const __bf16* g = A + (arow0 + mh * 128 + j * 64 + rA0) * K + kt * 64 + (cbA >> 1);
            gload_lds16(g, lds + AOFF(b, mh) + j * 8192 + ldsw);
        }
    };
    auto stageB = [&](int b, int kh, int kt) {
#pragma unroll
        for (int j = 0; j < 2; ++j) {
            const __bf16* g = Bt + (ncol0 + j * 128 + rB0) * K + kt * 64 + kh * 32 + (kbB >> 1);
            gload_lds16(g, lds + BOFF(b, kh) + j * 8192 + ldsw);
        }
    };

    // ---- fragment-read precompute (byte offsets, swizzled) ----
    const int xorv = (lane & 7) << 4;
    const int arow_part = (wr * 16 + l15) * 128;
    const int aco0 = arow_part + ((l16 * 16) ^ xorv);          // kh=0
    const int aco1 = arow_part + ((64 + l16 * 16) ^ xorv);     // kh=1
    const int bco = (wc * 16 + l15) * 64 + ((l16 ^ ((l15 >> 1) & 3)) * 16);

    f32x4 acc[8][4] = {};

#define BLOAD(bb, kh) \
    _Pragma("unroll") for (int g = 0; g < 4; ++g) \
        bfr[g] = *(const bf16x8*)(lds + BOFF(bb, kh) + g * 4096 + bco);

#define PHASE(bb, mq, kh, BL, STAGE, WAIT) { \
    BL \
    _Pragma("unroll") for (int f = 0; f < 4; ++f) \
        af[f] = *(const bf16x8*)(lds + AOFF(bb, mq) + f * 4096 + ((kh) ? aco1 : aco0)); \
    STAGE; \
    __builtin_amdgcn_s_barrier(); \
    asm volatile("s_waitcnt lgkmcnt(0)" ::: "memory"); \
    __builtin_amdgcn_sched_barrier(0); \
    __builtin_amdgcn_s_setprio(1); \
    _Pragma("unroll") for (int f = 0; f < 4; ++f) \
        _Pragma("unroll") for (int g = 0; g < 4; ++g) \
            acc[(mq) * 4 + f][g] = __builtin_amdgcn_mfma_f32_16x16x32_bf16(af[f], bfr[g], acc[(mq) * 4 + f][g], 0, 0, 0); \
    __builtin_amdgcn_s_setprio(0); \
    WAIT; \
    __builtin_amdgcn_s_barrier(); \
    __builtin_amdgcn_sched_barrier(0); \
}

    // ---- prologue: buf0 <- tile0 (4 halves), then 1.Bk0, 1.Ah0 of tile1 ----
    stageA(0, 0, 0); stageB(0, 0, 0); stageA(0, 1, 0); stageB(0, 1, 0);
    stageB(1, 0, 1); stageA(1, 0, 1);
    asm volatile("s_waitcnt vmcnt(4)" ::: "memory");
    __builtin_amdgcn_s_barrier();
    __builtin_amdgcn_sched_barrier(0);

    // ---- main loop: i=0..4, tiles (2i, 2i+1), staging up to tile 2i+3 ----
    for (int i = 0; i < 5; ++i) {
        const int t = 2 * i;
        bf16x8 af[4], bfr[4];
        PHASE(0, 0, 0, BLOAD(0, 0), stageB(1, 1, t + 1), );
        PHASE(0, 1, 0, ,            stageA(1, 1, t + 1), );
        PHASE(0, 0, 1, BLOAD(0, 1), stageB(0, 0, t + 2), );
        PHASE(0, 1, 1, ,            stageA(0, 0, t + 2), asm volatile("s_waitcnt vmcnt(4)" ::: "memory"));
        PHASE(1, 0, 0, BLOAD(1, 0), stageA(0, 1, t + 2), );
        PHASE(1, 1, 0, ,            stageB(0, 1, t + 2), );
        PHASE(1, 0, 1, BLOAD(1, 1), stageB(1, 0, t + 3), );
        PHASE(1, 1, 1, ,            stageA(1, 0, t + 3), asm volatile("s_waitcnt vmcnt(4)" ::: "memory"));
    }
    // ---- epilogue: tiles 10 (buf0), 11 (buf1); drain ----
    {
        bf16x8 af[4], bfr[4];
        PHASE(0, 0, 0, BLOAD(0, 0), stageB(1, 1, 11), );
        PHASE(0, 1, 0, ,            stageA(1, 1, 11), );
        PHASE(0, 0, 1, BLOAD(0, 1), , );
        PHASE(0, 1, 1, ,            , asm volatile("s_waitcnt vmcnt(0)" ::: "memory"));
        PHASE(1, 0, 0, BLOAD(1, 0), , );
        PHASE(1, 1, 0, ,            , );
        PHASE(1, 0, 1, BLOAD(1, 1), , );
        PHASE(1, 1, 1, ,            , );
    }
#undef PHASE
#undef BLOAD
#undef AOFF
#undef BOFF

    // ---- C write: row = arow0 + mf*32 + wr*16 + l16*4 + j, col = ncol0 + g*64 + wc*16 + l15
#pragma unroll
    for (int mf = 0; mf < 8; ++mf) {
        const int row = (int)arow0 + mf * 32 + wr * 16 + l16 * 4;
#pragma unroll
        for (int g = 0; g < 4; ++g) {
            const int col = (int)ncol0 + g * 64 + wc * 16 + l15;
            const float bv = bias[col];
#pragma unroll
            for (int j = 0; j < 4; ++j) {
                C[(long)(row + j) * N + col] = (OutT)(acc[mf][g][j] + bv);
            }
        }
    }
}

// ---------------- per-token 12x12 head attention ----------------
// qkv row: head-block g holds {q:0..63, k:64..127, v:128..191} at g*192.
// LDS stores rows in bf16 with head-block pitch 200 elems (400B stride ->
// banks rotate by 4 per head-block: no same-bank serialization).
#define HPITCH 200
__global__ __launch_bounds__(256) void k_attn(const __bf16* __restrict__ qkv,
                                              __bf16* __restrict__ out) {
    __shared__ __bf16 rows[4][12 * HPITCH];
    __shared__ float wts[4][144];
    const int w = threadIdx.x >> 6, lane = threadIdx.x & 63;
    const long token = (long)blockIdx.x * 4 + w;
    const __bf16* rp = qkv + token * QKVN;
    __bf16* row = rows[w];
    float* wt  = wts[w];

    // stage row (bf16, 16B chunks, 288 chunks; head h = c/24)
#pragma unroll
    for (int i = 0; i < 4; i++) {
        int c = i * 64 + lane;
        int h = c / 24;
        *(bf16x8*)(row + h * HPITCH + (c * 8 - h * 192)) = *(const bf16x8*)(rp + c * 8);
    }
    if (lane < 32) {
        int c = 256 + lane;
        int h = c / 24;
        *(bf16x8*)(row + h * HPITCH + (c * 8 - h * 192)) = *(const bf16x8*)(rp + c * 8);
    }
    __syncthreads();

    // scores[h][g] = q_h . k_g * scale  (144 dots of 64, bf16 reads)
    for (int p = lane; p < 144; p += 64) {
        int h = p / 12, g = p - h * 12;
        const __bf16* qp = row + h * HPITCH;
        const __bf16* kp = row + g * HPITCH + 64;
        float s = 0.f;
#pragma unroll
        for (int d = 0; d < 64; d += 8) {
            bf16x8 qv = *(const bf16x8*)(qp + d);
            bf16x8 kv = *(const bf16x8*)(kp + d);
#pragma unroll
            for (int j = 0; j < 8; j++) s += (float)qv[j] * (float)kv[j];
        }
        wt[p] = s * QK_SCALE;
    }
    __syncthreads();

    // softmax per row h (12 lanes)
    if (lane < 12) {
        float s[12];
#pragma unroll
        for (int g = 0; g < 12; g++) s[g] = wt[lane * 12 + g];
        float m = s[0];
#pragma unroll
        for (int g = 1; g < 12; g++) m = fmaxf(m, s[g]);
        float sum = 0.f;
#pragma unroll
        for (int g = 0; g < 12; g++) { s[g] = __expf(s[g] - m); sum += s[g]; }
        float inv = 1.0f / sum;
#pragma unroll
        for (int g = 0; g < 12; g++) wt[lane * 12 + g] = s[g] * inv;
    }
    __syncthreads();

    // PV: V held in registers (lane = d); wt reads are wave-broadcast
    float vr[12];
#pragma unroll
    for (int g = 0; g < 12; g++) vr[g] = (float)row[g * HPITCH + 128 + lane];
#pragma unroll
    for (int h = 0; h < 12; h++) {
        float a = 0.f;
#pragma unroll
        for (int g = 0; g < 12; g++) a += wt[h * 12 + g] * vr[g];
        out[token * EMBED + h * 64 + lane] = (__bf16)a;
    }
}

extern "C" void kernel_launch(void* const* d_in, const int* in_sizes, int n_in,
                              void* d_out, int out_size, void* d_ws, size_t ws_size,
                              hipStream_t stream) {
    const float* x     = (const float*)d_in[0];
    const float* w_qkv = (const float*)d_in[1];
    const float* b_qkv = (const float*)d_in[2];
    const float* w_o   = (const float*)d_in[3];
    const float* b_o   = (const float*)d_in[4];
    float* out = (float*)d_out;

    char* ws = (char*)d_ws;
    size_t off = 0;
    auto take = [&](size_t bytes) {
        char* p = ws + off;
        off += (bytes + 255) & ~(size_t)255;
        return p;
    };
    __bf16* wqkvt = (__bf16*)take((size_t)QKVN * EMBED * 2);
    __bf16* wot   = (__bf16*)take((size_t)EMBED * EMBED * 2);
    __bf16* xb    = (__bf16*)take((size_t)TOKENS * EMBED * 2);
    __bf16* qkvb  = (__bf16*)take((size_t)TOKENS * QKVN * 2);
    __bf16* attno = xb;  // x_bf16 dead after GEMM1; reuse

    // allow 128KB dynamic LDS (idempotent host-side config)
    static bool attr_done = false;
    if (!attr_done) {
        hipFuncSetAttribute((const void*)gemm8<__bf16>,
                            hipFuncAttributeMaxDynamicSharedMemorySize, 131072);
        hipFuncSetAttribute((const void*)gemm8<float>,
                            hipFuncAttributeMaxDynamicSharedMemorySize, 131072);
        attr_done = true;
    }

    int n4 = TOKENS * EMBED / 4;
    k_cvt_bf16<<<2048, 256, 0, stream>>>((const float4*)x, (bf16x4*)xb, n4);

    dim3 tb(32, 8);
    k_transpose_cvt<<<dim3(QKVN / 32, EMBED / 32), tb, 0, stream>>>(w_qkv, wqkvt, EMBED, QKVN);
    k_transpose_cvt<<<dim3(EMBED / 32, EMBED / 32), tb, 0, stream>>>(w_o, wot, EMBED, EMBED);

    // GEMM1: qkv = x @ w_qkv + b_qkv   -> bf16  (1152 wg, %8==0)
    gemm8<__bf16><<<(TOKENS / 256) * (QKVN / 256), 512, 131072, stream>>>(
        xb, wqkvt, b_qkv, qkvb, QKVN);

    k_attn<<<TOKENS / 4, 256, 0, stream>>>(qkvb, attno);

    // GEMM2: out = attn_out @ w_o + b_o  -> f32  (384 wg, %8==0)
    gemm8<float><<<(TOKENS / 256) * (EMBED / 256), 512, 131072, stream>>>(
        attno, wot, b_o, out, EMBED);
}

// Round 4
// 272.729 us; speedup vs baseline: 1.3841x; 1.0063x over previous
//
#include <hip/hip_runtime.h>
#include <hip/hip_bf16.h>

#define EMBED 768
#define HEADS 12
#define TOKENS 32768          // B*S = 32*1024
#define QKVN  (3*EMBED)       // 2304
#define KDIM  768
#define QK_SCALE 0.03608439182435161f  // 768^-0.5

typedef __attribute__((ext_vector_type(8))) __bf16 bf16x8;
typedef __attribute__((ext_vector_type(4))) __bf16 bf16x4;
typedef __attribute__((ext_vector_type(4))) float  f32x4;

__device__ __forceinline__ void gload_lds16(const void* gptr, void* lptr) {
    __builtin_amdgcn_global_load_lds(
        (const __attribute__((address_space(1))) void*)gptr,
        (__attribute__((address_space(3))) void*)lptr,
        16, 0, 0);
}

// ---------------- f32 -> bf16 cast (vectorized) ----------------
__global__ __launch_bounds__(256) void k_cvt_bf16(const float4* __restrict__ src,
                                                  bf16x4* __restrict__ dst, int n4) {
    int i = blockIdx.x * blockDim.x + threadIdx.x;
    int stride = gridDim.x * blockDim.x;
    for (; i < n4; i += stride) {
        float4 f = src[i];
        bf16x4 o;
        o[0] = (__bf16)f.x; o[1] = (__bf16)f.y; o[2] = (__bf16)f.z; o[3] = (__bf16)f.w;
        dst[i] = o;
    }
}

// ---------------- transpose + cast: src [R][C] f32 -> dst [C][R] bf16 ----------------
__global__ __launch_bounds__(256) void k_transpose_cvt(const float* __restrict__ src,
                                                       __bf16* __restrict__ dst,
                                                       int R, int C) {
    __shared__ float tile[32][33];
    int c0 = blockIdx.x * 32, r0 = blockIdx.y * 32;
    int tx = threadIdx.x, ty = threadIdx.y;   // 32 x 8
#pragma unroll
    for (int j = 0; j < 4; j++) {
        int r = r0 + ty + j * 8;
        tile[ty + j * 8][tx] = src[(long)r * C + c0 + tx];
    }
    __syncthreads();
#pragma unroll
    for (int j = 0; j < 4; j++) {
        int c = c0 + ty + j * 8;
        dst[(long)c * R + r0 + tx] = (__bf16)tile[tx][ty + j * 8];
    }
}

// ================= 256x256 8-phase bf16 MFMA GEMM (K=768) =================
// Register-double-buffered fragments: phase p issues ds_reads for p+1 into
// the alternate reg set and waits only lgkmcnt(N_issued) -> LDS read service
// overlaps MFMA.  Stage slots + counted vmcnt re-derived (FIFO ledger):
//  P1:b0.Bk0(t+2) P3:b0.Ah0 P4:b0.Bk1+b0.Ah1 P5:b1.Bk0(t+3) P6:b1.Bk1
//  P7:b1.Ah0+b1.Ah1 ; waits vm6 except vm4 at P2,P3; epilogue vm2@E2,vm0@E3.
template <typename OutT>
__global__ __launch_bounds__(512, 2) void gemm8(const __bf16* __restrict__ A,
                                                const __bf16* __restrict__ Bt,
                                                const float* __restrict__ bias,
                                                OutT* __restrict__ C, int N) {
    extern __shared__ char lds[];
    const int tid = threadIdx.x;
    const int w = tid >> 6, lane = tid & 63;
    const int wr = w >> 2, wc = w & 3;
    const int l15 = lane & 15, l16 = lane >> 4;
    const int K = KDIM;

    // XCD-aware block swizzle (nwg % 8 == 0 for both our grids)
    const int nbx = N >> 8;
    const int nwg = gridDim.x;
    const int cpx = nwg >> 3;
    const int bid = blockIdx.x;
    const int swz = (bid & 7) * cpx + (bid >> 3);
    const int brow = swz / nbx, bcol = swz % nbx;
    const long arow0 = (long)brow * 256;
    const long ncol0 = (long)bcol * 256;

#define AOFF(b, mh) (((b) * 2 + (mh)) * 16384)
#define BOFF(b, kh) (65536 + ((b) * 2 + (kh)) * 16384)

    // ---- staging precompute (pre-swizzled global source, linear LDS dest) ----
    const int rA0 = tid >> 3;                                  // 0..63
    const int cbA = ((tid & 7) * 16) ^ ((rA0 & 7) << 4);       // byte col in A row
    const int rB0 = tid >> 2;                                  // 0..127
    const int kbB = (((tid & 3) ^ ((tid >> 3) & 3)) * 16);     // byte col in B khalf row
    const int ldsw = w * 1024;                                 // wave slice

    auto stageA = [&](int b, int mh, int kt) {
#pragma unroll
        for (int j = 0; j < 2; ++j) {
            const __bf16* g = A + (arow0 + mh * 128 + j * 64 + rA0) * K + kt * 64 + (cbA >> 1);
            gload_lds16(g, lds + AOFF(b, mh) + j * 8192 + ldsw);
        }
    };
    auto stageB = [&](int b, int kh, int kt) {
#pragma unroll
        for (int j = 0; j < 2; ++j) {
            const __bf16* g = Bt + (ncol0 + j * 128 + rB0) * K + kt * 64 + kh * 32 + (kbB >> 1);
            gload_lds16(g, lds + BOFF(b, kh) + j * 8192 + ldsw);
        }
    };

    // ---- fragment-read precompute (byte offsets, swizzled) ----
    const int xorv = (lane & 7) << 4;
    const int arow_part = (wr * 16 + l15) * 128;
    const int aco0 = arow_part + ((l16 * 16) ^ xorv);          // kh=0
    const int aco1 = arow_part + ((64 + l16 * 16) ^ xorv);     // kh=1
    const int bco = (wc * 16 + l15) * 64 + ((l16 ^ ((l15 >> 1) & 3)) * 16);

    f32x4 acc[8][4] = {};

#define RD_A(DST, BB, MQ, KH) do { \
    _Pragma("unroll") for (int f = 0; f < 4; ++f) \
        DST[f] = *(const bf16x8*)(lds + AOFF(BB, MQ) + f * 4096 + ((KH) ? aco1 : aco0)); \
} while (0)
#define RD_B(DST, BB, KH) do { \
    _Pragma("unroll") for (int g = 0; g < 4; ++g) \
        DST[g] = *(const bf16x8*)(lds + BOFF(BB, KH) + g * 4096 + bco); \
} while (0)
#define VM6 asm volatile("s_waitcnt vmcnt(6)" ::: "memory")
#define VM4 asm volatile("s_waitcnt vmcnt(4)" ::: "memory")
#define VM2 asm volatile("s_waitcnt vmcnt(2)" ::: "memory")
#define VM0 asm volatile("s_waitcnt vmcnt(0)" ::: "memory")

#define PHASE(MQ, AF, BF, RD, ST, VW, LG) do { \
    RD; ST; \
    __builtin_amdgcn_s_barrier(); \
    asm volatile("s_waitcnt lgkmcnt(" LG ")" ::: "memory"); \
    __builtin_amdgcn_sched_barrier(0); \
    __builtin_amdgcn_s_setprio(1); \
    _Pragma("unroll") for (int f = 0; f < 4; ++f) \
        _Pragma("unroll") for (int g = 0; g < 4; ++g) \
            acc[(MQ) * 4 + f][g] = __builtin_amdgcn_mfma_f32_16x16x32_bf16(AF[f], BF[g], acc[(MQ) * 4 + f][g], 0, 0, 0); \
    __builtin_amdgcn_s_setprio(0); \
    VW; \
    __builtin_amdgcn_s_barrier(); \
    __builtin_amdgcn_sched_barrier(0); \
} while (0)

    // ---- prologue: tile0 -> buf0, tile1 -> buf1; preload P0's fragments ----
    stageA(0, 0, 0); stageB(0, 0, 0); stageA(0, 1, 0); stageB(0, 1, 0);
    stageB(1, 0, 1); stageB(1, 1, 1); stageA(1, 0, 1); stageA(1, 1, 1);
    VM6;                                 // b0 all + b1.Bk0 landed
    __builtin_amdgcn_s_barrier();
    __builtin_amdgcn_sched_barrier(0);
    bf16x8 afs0[4], afs1[4], bfs0[4], bfs1[4];
    RD_A(afs0, 0, 0, 0); RD_B(bfs0, 0, 0);
    asm volatile("s_waitcnt lgkmcnt(0)" ::: "memory");
    __builtin_amdgcn_sched_barrier(0);
    __builtin_amdgcn_s_barrier();

    // ---- main loop: i=0..4, tiles (2i, 2i+1); stages for tiles 2i+2, 2i+3 ----
    for (int i = 0; i < 5; ++i) {
        const int t = 2 * i;
        PHASE(0, afs0, bfs0, RD_A(afs1, 0, 1, 0),                       ,                                    VM6, "4");
        PHASE(1, afs1, bfs0, RD_A(afs0, 0, 0, 1); RD_B(bfs1, 0, 1),     stageB(0, 0, t + 2),                 VM6, "8");
        PHASE(0, afs0, bfs1, RD_A(afs1, 0, 1, 1),                       ,                                    VM4, "4");
        PHASE(1, afs1, bfs1, RD_A(afs0, 1, 0, 0); RD_B(bfs0, 1, 0),     stageA(0, 0, t + 2),                 VM4, "8");
        PHASE(0, afs0, bfs0, RD_A(afs1, 1, 1, 0),                       stageB(0, 1, t + 2); stageA(0, 1, t + 2), VM6, "4");
        PHASE(1, afs1, bfs0, RD_A(afs0, 1, 0, 1); RD_B(bfs1, 1, 1),     stageB(1, 0, t + 3),                 VM6, "8");
        PHASE(0, afs0, bfs1, RD_A(afs1, 1, 1, 1),                       stageB(1, 1, t + 3),                 VM6, "4");
        PHASE(1, afs1, bfs1, RD_A(afs0, 0, 0, 0); RD_B(bfs0, 0, 0),     stageA(1, 0, t + 3); stageA(1, 1, t + 3), VM6, "8");
    }
    // ---- epilogue: tiles 10 (buf0), 11 (buf1); drain staging pipeline ----
    PHASE(0, afs0, bfs0, RD_A(afs1, 0, 1, 0),                       , ,    "4");
    PHASE(1, afs1, bfs0, RD_A(afs0, 0, 0, 1); RD_B(bfs1, 0, 1),     , ,    "8");
    PHASE(0, afs0, bfs1, RD_A(afs1, 0, 1, 1),                       , VM2, "4");
    PHASE(1, afs1, bfs1, RD_A(afs0, 1, 0, 0); RD_B(bfs0, 1, 0),     , VM0, "8");
    PHASE(0, afs0, bfs0, RD_A(afs1, 1, 1, 0),                       , ,    "4");
    PHASE(1, afs1, bfs0, RD_A(afs0, 1, 0, 1); RD_B(bfs1, 1, 1),     , ,    "8");
    PHASE(0, afs0, bfs1, RD_A(afs1, 1, 1, 1),                       , ,    "4");
    PHASE(1, afs1, bfs1, ,                                          , ,    "0");
#undef PHASE
#undef RD_A
#undef RD_B
#undef AOFF
#undef BOFF

    // ---- C write: row = arow0 + mf*32 + wr*16 + l16*4 + j, col = ncol0 + g*64 + wc*16 + l15
#pragma unroll
    for (int mf = 0; mf < 8; ++mf) {
        const int row = (int)arow0 + mf * 32 + wr * 16 + l16 * 4;
#pragma unroll
        for (int g = 0; g < 4; ++g) {
            const int col = (int)ncol0 + g * 64 + wc * 16 + l15;
            const float bv = bias[col];
#pragma unroll
            for (int j = 0; j < 4; ++j) {
                C[(long)(row + j) * N + col] = (OutT)(acc[mf][g][j] + bv);
            }
        }
    }
}

// ---------------- per-token 12x12 head attention ----------------
// qkv row: head-block g holds {q:0..63, k:64..127, v:128..191} at g*192.
// LDS stores rows in bf16 with head-block pitch 200 elems (400B stride ->
// banks rotate by 4 per head-block: no same-bank serialization).
#define HPITCH 200
__global__ __launch_bounds__(256) void k_attn(const __bf16* __restrict__ qkv,
                                              __bf16* __restrict__ out) {
    __shared__ __bf16 rows[4][12 * HPITCH];
    __shared__ float wts[4][144];
    const int w = threadIdx.x >> 6, lane = threadIdx.x & 63;
    const long token = (long)blockIdx.x * 4 + w;
    const __bf16* rp = qkv + token * QKVN;
    __bf16* row = rows[w];
    float* wt  = wts[w];

    // stage row (bf16, 16B chunks, 288 chunks; head h = c/24)
#pragma unroll
    for (int i = 0; i < 4; i++) {
        int c = i * 64 + lane;
        int h = c / 24;
        *(bf16x8*)(row + h * HPITCH + (c * 8 - h * 192)) = *(const bf16x8*)(rp + c * 8);
    }
    if (lane < 32) {
        int c = 256 + lane;
        int h = c / 24;
        *(bf16x8*)(row + h * HPITCH + (c * 8 - h * 192)) = *(const bf16x8*)(rp + c * 8);
    }
    __syncthreads();

    // scores[h][g] = q_h . k_g * scale  (144 dots of 64, bf16 reads)
    for (int p = lane; p < 144; p += 64) {
        int h = p / 12, g = p - h * 12;
        const __bf16* qp = row + h * HPITCH;
        const __bf16* kp = row + g * HPITCH + 64;
        float s = 0.f;
#pragma unroll
        for (int d = 0; d < 64; d += 8) {
            bf16x8 qv = *(const bf16x8*)(qp + d);
            bf16x8 kv = *(const bf16x8*)(kp + d);
#pragma unroll
            for (int j = 0; j < 8; j++) s += (float)qv[j] * (float)kv[j];
        }
        wt[p] = s * QK_SCALE;
    }
    __syncthreads();

    // softmax per row h (12 lanes)
    if (lane < 12) {
        float s[12];
#pragma unroll
        for (int g = 0; g < 12; g++) s[g] = wt[lane * 12 + g];
        float m = s[0];
#pragma unroll
        for (int g = 1; g < 12; g++) m = fmaxf(m, s[g]);
        float sum = 0.f;
#pragma unroll
        for (int g = 0; g < 12; g++) { s[g] = __expf(s[g] - m); sum += s[g]; }
        float inv = 1.0f / sum;
#pragma unroll
        for (int g = 0; g < 12; g++) wt[lane * 12 + g] = s[g] * inv;
    }
    __syncthreads();

    // PV: V held in registers (lane = d); wt reads are wave-broadcast
    float vr[12];
#pragma unroll
    for (int g = 0; g < 12; g++) vr[g] = (float)row[g * HPITCH + 128 + lane];
#pragma unroll
    for (int h = 0; h < 12; h++) {
        float a = 0.f;
#pragma unroll
        for (int g = 0; g < 12; g++) a += wt[h * 12 + g] * vr[g];
        out[token * EMBED + h * 64 + lane] = (__bf16)a;
    }
}

extern "C" void kernel_launch(void* const* d_in, const int* in_sizes, int n_in,
                              void* d_out, int out_size, void* d_ws, size_t ws_size,
                              hipStream_t stream) {
    const float* x     = (const float*)d_in[0];
    const float* w_qkv = (const float*)d_in[1];
    const float* b_qkv = (const float*)d_in[2];
    const float* w_o   = (const float*)d_in[3];
    const float* b_o   = (const float*)d_in[4];
    float* out = (float*)d_out;

    char* ws = (char*)d_ws;
    size_t off = 0;
    auto take = [&](size_t bytes) {
        char* p = ws + off;
        off += (bytes + 255) & ~(size_t)255;
        return p;
    };
    __bf16* wqkvt = (__bf16*)take((size_t)QKVN * EMBED * 2);
    __bf16* wot   = (__bf16*)take((size_t)EMBED * EMBED * 2);
    __bf16* xb    = (__bf16*)take((size_t)TOKENS * EMBED * 2);
    __bf16* qkvb  = (__bf16*)take((size_t)TOKENS * QKVN * 2);
    __bf16* attno = xb;  // x_bf16 dead after GEMM1; reuse

    // allow 128KB dynamic LDS (idempotent host-side config)
    static bool attr_done = false;
    if (!attr_done) {
        hipFuncSetAttribute((const void*)gemm8<__bf16>,
                            hipFuncAttributeMaxDynamicSharedMemorySize, 131072);
        hipFuncSetAttribute((const void*)gemm8<float>,
                            hipFuncAttributeMaxDynamicSharedMemorySize, 131072);
        attr_done = true;
    }

    int n4 = TOKENS * EMBED / 4;
    k_cvt_bf16<<<2048, 256, 0, stream>>>((const float4*)x, (bf16x4*)xb, n4);

    dim3 tb(32, 8);
    k_transpose_cvt<<<dim3(QKVN / 32, EMBED / 32), tb, 0, stream>>>(w_qkv, wqkvt, EMBED, QKVN);
    k_transpose_cvt<<<dim3(EMBED / 32, EMBED / 32), tb, 0, stream>>>(w_o, wot, EMBED, EMBED);

    // GEMM1: qkv = x @ w_qkv + b_qkv   -> bf16  (1152 wg, %8==0)
    gemm8<__bf16><<<(TOKENS / 256) * (QKVN / 256), 512, 131072, stream>>>(
        xb, wqkvt, b_qkv, qkvb, QKVN);

    k_attn<<<TOKENS / 4, 256, 0, stream>>>(qkvb, attno);

    // GEMM2: out = attn_out @ w_o + b_o  -> f32  (384 wg, %8==0)
    gemm8<float><<<(TOKENS / 256) * (EMBED / 256), 512, 131072, stream>>>(
        attno, wot, b_o, out, EMBED);
}

// Round 5
// 253.929 us; speedup vs baseline: 1.4866x; 1.0740x over previous
//
#include <hip/hip_runtime.h>
#include <hip/hip_bf16.h>

#define EMBED 768
#define HEADS 12
#define TOKENS 32768          // B*S = 32*1024
#define QKVN  (3*EMBED)       // 2304
#define KDIM  768
#define QK_SCALE 0.03608439182435161f  // 768^-0.5

typedef __attribute__((ext_vector_type(8))) __bf16 bf16x8;
typedef __attribute__((ext_vector_type(4))) __bf16 bf16x4;
typedef __attribute__((ext_vector_type(4))) float  f32x4;

__device__ __forceinline__ void gload_lds16(const void* gptr, void* lptr) {
    __builtin_amdgcn_global_load_lds(
        (const __attribute__((address_space(1))) void*)gptr,
        (__attribute__((address_space(3))) void*)lptr,
        16, 0, 0);
}

// ---------------- f32 -> bf16 cast (vectorized) ----------------
__global__ __launch_bounds__(256) void k_cvt_bf16(const float4* __restrict__ src,
                                                  bf16x4* __restrict__ dst, int n4) {
    int i = blockIdx.x * blockDim.x + threadIdx.x;
    int stride = gridDim.x * blockDim.x;
    for (; i < n4; i += stride) {
        float4 f = src[i];
        bf16x4 o;
        o[0] = (__bf16)f.x; o[1] = (__bf16)f.y; o[2] = (__bf16)f.z; o[3] = (__bf16)f.w;
        dst[i] = o;
    }
}

// ---------------- transpose + cast: src [R][C] f32 -> dst [C][R] bf16 ----------------
__global__ __launch_bounds__(256) void k_transpose_cvt(const float* __restrict__ src,
                                                       __bf16* __restrict__ dst,
                                                       int R, int C) {
    __shared__ float tile[32][33];
    int c0 = blockIdx.x * 32, r0 = blockIdx.y * 32;
    int tx = threadIdx.x, ty = threadIdx.y;   // 32 x 8
#pragma unroll
    for (int j = 0; j < 4; j++) {
        int r = r0 + ty + j * 8;
        tile[ty + j * 8][tx] = src[(long)r * C + c0 + tx];
    }
    __syncthreads();
#pragma unroll
    for (int j = 0; j < 4; j++) {
        int c = c0 + ty + j * 8;
        dst[(long)c * R + r0 + tx] = (__bf16)tile[tx][ty + j * 8];
    }
}

// ============ 128x256 bf16 MFMA GEMM, BK=32, 4 waves, 2 blocks/CU ============
// C[M][N] = A[M][K] @ Bt[N][K]^T + bias.  Triple-buffered LDS (72KB):
// A[3][128][32] @ 0, B[3][256][32] @ 24KB, 64B rows, XOR-swizzle
// chunk' = chunk ^ ((row>>1)&3)  (R2-measured zero-conflict pattern).
// Per K-tile: read 8 A-frags + 4 B-frags (b128), stage K-tile t+2 (6 loads),
// barrier, lgkm(0), 32 MFMA, vmcnt(6), barrier.  Sibling block on the CU
// fills all sync stalls (the point of this structure).
template <typename OutT>
__global__ __launch_bounds__(256, 2) void gemm_kt(const __bf16* __restrict__ A,
                                                  const __bf16* __restrict__ Bt,
                                                  const float* __restrict__ bias,
                                                  OutT* __restrict__ C, int N) {
    extern __shared__ char lds[];
    const int tid = threadIdx.x;
    const int w = tid >> 6, lane = tid & 63;
    const int wc = w;                         // wave owns 64 N-cols
    const int l15 = lane & 15, l16 = lane >> 4;
    const int K = KDIM;

    // XCD-aware block swizzle (grid % 8 == 0 for both our grids)
    const int nbx = N >> 8;                   // N-tiles of 256
    const int nwg = gridDim.x;
    const int cpx = nwg >> 3;
    const int bid = blockIdx.x;
    const int swz = (bid & 7) * cpx + (bid >> 3);
    const int brow = swz / nbx, bcol = swz % nbx;
    const long arow0 = (long)brow * 128;
    const long ncol0 = (long)bcol * 256;

    // ---- staging precompute (pre-swizzled global source, linear LDS dest) ----
    const int rowS = w * 16 + (lane >> 2);                 // 0..63 per 64-row group
    const int cgS  = (((lane & 3) ^ ((lane >> 3) & 3)) * 8); // element offset in row
    const int wofs = w * 1024;

    auto stageA = [&](int r, int kt) {
#pragma unroll
        for (int j = 0; j < 2; ++j)
            gload_lds16(A + (arow0 + j * 64 + rowS) * K + kt * 32 + cgS,
                        lds + r * 8192 + j * 4096 + wofs);
    };
    auto stageB = [&](int r, int kt) {
#pragma unroll
        for (int j = 0; j < 4; ++j)
            gload_lds16(Bt + (ncol0 + j * 64 + rowS) * K + kt * 32 + cgS,
                        lds + 24576 + r * 16384 + j * 4096 + wofs);
    };

    // ---- fragment-read byte offsets (swizzled; R2 zero-conflict form) ----
    const int swz16 = (l16 ^ ((l15 >> 1) & 3)) * 16;
    const int aco = l15 * 64 + swz16;                      // + mf*1024
    const int bco = wc * 4096 + l15 * 64 + swz16;          // + n*1024

    f32x4 acc[8][4] = {};

#define VM6 asm volatile("s_waitcnt vmcnt(6)" ::: "memory")
#define VM0 asm volatile("s_waitcnt vmcnt(0)" ::: "memory")
#define KSTEP(R, STAGE, VW) do { \
    bf16x8 af[8], bfv[4]; \
    _Pragma("unroll") for (int mf = 0; mf < 8; ++mf) \
        af[mf] = *(const bf16x8*)(lds + (R) * 8192 + mf * 1024 + aco); \
    _Pragma("unroll") for (int n = 0; n < 4; ++n) \
        bfv[n] = *(const bf16x8*)(lds + 24576 + (R) * 16384 + n * 1024 + bco); \
    STAGE; \
    __builtin_amdgcn_s_barrier(); \
    asm volatile("s_waitcnt lgkmcnt(0)" ::: "memory"); \
    __builtin_amdgcn_sched_barrier(0); \
    __builtin_amdgcn_s_setprio(1); \
    _Pragma("unroll") for (int mf = 0; mf < 8; ++mf) \
        _Pragma("unroll") for (int n = 0; n < 4; ++n) \
            acc[mf][n] = __builtin_amdgcn_mfma_f32_16x16x32_bf16(af[mf], bfv[n], acc[mf][n], 0, 0, 0); \
    __builtin_amdgcn_s_setprio(0); \
    VW; \
    __builtin_amdgcn_s_barrier(); \
    __builtin_amdgcn_sched_barrier(0); \
} while (0)

    // ---- prologue: stage K-tiles 0,1 into bufs 0,1; wait tile0 landed ----
    stageA(0, 0); stageB(0, 0);
    stageA(1, 1); stageB(1, 1);
    VM6;
    __builtin_amdgcn_s_barrier();
    __builtin_amdgcn_sched_barrier(0);

    // ---- main: t = 0..20 (7x3), stage t+2 into buf (t+2)%3, vmcnt(6) ----
    for (int t = 0; t < 21; t += 3) {
        KSTEP(0, stageA(2, t + 2); stageB(2, t + 2), VM6);
        KSTEP(1, stageA(0, t + 3); stageB(0, t + 3), VM6);
        KSTEP(2, stageA(1, t + 4); stageB(1, t + 4), VM6);
    }
    // ---- peel t=21 (stage 23), t=22 (drain), t=23 ----
    KSTEP(0, stageA(2, 23); stageB(2, 23), VM6);
    KSTEP(1, , VM0);
    KSTEP(2, , );
#undef KSTEP
#undef VM6
#undef VM0

    // ---- C write: row = arow0 + mf*16 + l16*4 + j, col = ncol0 + wc*64 + n*16 + l15
#pragma unroll
    for (int mf = 0; mf < 8; ++mf) {
        const int row = (int)arow0 + mf * 16 + l16 * 4;
#pragma unroll
        for (int n = 0; n < 4; ++n) {
            const int col = (int)ncol0 + wc * 64 + n * 16 + l15;
            const float bv = bias[col];
#pragma unroll
            for (int j = 0; j < 4; ++j) {
                C[(long)(row + j) * N + col] = (OutT)(acc[mf][n][j] + bv);
            }
        }
    }
}

// ---------------- per-token 12x12 head attention ----------------
// qkv row: head-block g holds {q:0..63, k:64..127, v:128..191} at g*192.
// LDS stores rows in bf16 with head-block pitch 200 elems (400B stride ->
// banks rotate by 4 per head-block: no same-bank serialization).
#define HPITCH 200
__global__ __launch_bounds__(256) void k_attn(const __bf16* __restrict__ qkv,
                                              __bf16* __restrict__ out) {
    __shared__ __bf16 rows[4][12 * HPITCH];
    __shared__ float wts[4][144];
    const int w = threadIdx.x >> 6, lane = threadIdx.x & 63;
    const long token = (long)blockIdx.x * 4 + w;
    const __bf16* rp = qkv + token * QKVN;
    __bf16* row = rows[w];
    float* wt  = wts[w];

    // stage row (bf16, 16B chunks, 288 chunks; head h = c/24)
#pragma unroll
    for (int i = 0; i < 4; i++) {
        int c = i * 64 + lane;
        int h = c / 24;
        *(bf16x8*)(row + h * HPITCH + (c * 8 - h * 192)) = *(const bf16x8*)(rp + c * 8);
    }
    if (lane < 32) {
        int c = 256 + lane;
        int h = c / 24;
        *(bf16x8*)(row + h * HPITCH + (c * 8 - h * 192)) = *(const bf16x8*)(rp + c * 8);
    }
    __syncthreads();

    // scores[h][g] = q_h . k_g * scale  (144 dots of 64, bf16 reads)
    for (int p = lane; p < 144; p += 64) {
        int h = p / 12, g = p - h * 12;
        const __bf16* qp = row + h * HPITCH;
        const __bf16* kp = row + g * HPITCH + 64;
        float s = 0.f;
#pragma unroll
        for (int d = 0; d < 64; d += 8) {
            bf16x8 qv = *(const bf16x8*)(qp + d);
            bf16x8 kv = *(const bf16x8*)(kp + d);
#pragma unroll
            for (int j = 0; j < 8; j++) s += (float)qv[j] * (float)kv[j];
        }
        wt[p] = s * QK_SCALE;
    }
    __syncthreads();

    // softmax per row h (12 lanes)
    if (lane < 12) {
        float s[12];
#pragma unroll
        for (int g = 0; g < 12; g++) s[g] = wt[lane * 12 + g];
        float m = s[0];
#pragma unroll
        for (int g = 1; g < 12; g++) m = fmaxf(m, s[g]);
        float sum = 0.f;
#pragma unroll
        for (int g = 0; g < 12; g++) { s[g] = __expf(s[g] - m); sum += s[g]; }
        float inv = 1.0f / sum;
#pragma unroll
        for (int g = 0; g < 12; g++) wt[lane * 12 + g] = s[g] * inv;
    }
    __syncthreads();

    // PV: V held in registers (lane = d); wt reads are wave-broadcast
    float vr[12];
#pragma unroll
    for (int g = 0; g < 12; g++) vr[g] = (float)row[g * HPITCH + 128 + lane];
#pragma unroll
    for (int h = 0; h < 12; h++) {
        float a = 0.f;
#pragma unroll
        for (int g = 0; g < 12; g++) a += wt[h * 12 + g] * vr[g];
        out[token * EMBED + h * 64 + lane] = (__bf16)a;
    }
}

extern "C" void kernel_launch(void* const* d_in, const int* in_sizes, int n_in,
                              void* d_out, int out_size, void* d_ws, size_t ws_size,
                              hipStream_t stream) {
    const float* x     = (const float*)d_in[0];
    const float* w_qkv = (const float*)d_in[1];
    const float* b_qkv = (const float*)d_in[2];
    const float* w_o   = (const float*)d_in[3];
    const float* b_o   = (const float*)d_in[4];
    float* out = (float*)d_out;

    char* ws = (char*)d_ws;
    size_t off = 0;
    auto take = [&](size_t bytes) {
        char* p = ws + off;
        off += (bytes + 255) & ~(size_t)255;
        return p;
    };
    __bf16* wqkvt = (__bf16*)take((size_t)QKVN * EMBED * 2);
    __bf16* wot   = (__bf16*)take((size_t)EMBED * EMBED * 2);
    __bf16* xb    = (__bf16*)take((size_t)TOKENS * EMBED * 2);
    __bf16* qkvb  = (__bf16*)take((size_t)TOKENS * QKVN * 2);
    __bf16* attno = xb;  // x_bf16 dead after GEMM1; reuse

    // allow 72KB dynamic LDS (idempotent host-side config)
    static bool attr_done = false;
    if (!attr_done) {
        hipFuncSetAttribute((const void*)gemm_kt<__bf16>,
                            hipFuncAttributeMaxDynamicSharedMemorySize, 131072);
        hipFuncSetAttribute((const void*)gemm_kt<float>,
                            hipFuncAttributeMaxDynamicSharedMemorySize, 131072);
        attr_done = true;
    }

    int n4 = TOKENS * EMBED / 4;
    k_cvt_bf16<<<2048, 256, 0, stream>>>((const float4*)x, (bf16x4*)xb, n4);

    dim3 tb(32, 8);
    k_transpose_cvt<<<dim3(QKVN / 32, EMBED / 32), tb, 0, stream>>>(w_qkv, wqkvt, EMBED, QKVN);
    k_transpose_cvt<<<dim3(EMBED / 32, EMBED / 32), tb, 0, stream>>>(w_o, wot, EMBED, EMBED);

    // GEMM1: qkv = x @ w_qkv + b_qkv -> bf16   (2304 wg, %8==0)
    gemm_kt<__bf16><<<(TOKENS / 128) * (QKVN / 256), 256, 73728, stream>>>(
        xb, wqkvt, b_qkv, qkvb, QKVN);

    k_attn<<<TOKENS / 4, 256, 0, stream>>>(qkvb, attno);

    // GEMM2: out = attn_out @ w_o + b_o -> f32  (768 wg, %8==0)
    gemm_kt<float><<<(TOKENS / 128) * (EMBED / 256), 256, 73728, stream>>>(
        attno, wot, b_o, out, EMBED);
}

// Round 6
// 238.661 us; speedup vs baseline: 1.5817x; 1.0640x over previous
//
#include <hip/hip_runtime.h>
#include <hip/hip_bf16.h>

#define EMBED 768
#define HEADS 12
#define TOKENS 32768          // B*S = 32*1024
#define QKVN  (3*EMBED)       // 2304
#define KDIM  768
#define NKT   (KDIM/64)       // 12 K-tiles of 64
#define QK_SCALE 0.03608439182435161f  // 768^-0.5

typedef __attribute__((ext_vector_type(8))) __bf16 bf16x8;
typedef __attribute__((ext_vector_type(4))) __bf16 bf16x4;
typedef __attribute__((ext_vector_type(4))) float  f32x4;

__device__ __forceinline__ void gload_lds16(const void* gptr, void* lptr) {
    __builtin_amdgcn_global_load_lds(
        (const __attribute__((address_space(1))) void*)gptr,
        (__attribute__((address_space(3))) void*)lptr,
        16, 0, 0);
}

// ---------------- f32 -> bf16 cast (vectorized) ----------------
__global__ __launch_bounds__(256) void k_cvt_bf16(const float4* __restrict__ src,
                                                  bf16x4* __restrict__ dst, int n4) {
    int i = blockIdx.x * blockDim.x + threadIdx.x;
    int stride = gridDim.x * blockDim.x;
    for (; i < n4; i += stride) {
        float4 f = src[i];
        bf16x4 o;
        o[0] = (__bf16)f.x; o[1] = (__bf16)f.y; o[2] = (__bf16)f.z; o[3] = (__bf16)f.w;
        dst[i] = o;
    }
}

// -------- pack weights [K][N] f32 -> MFMA-fragment order bf16 --------
// BF[kt][n16][ks][lane][8]: lane l holds col n16*16+(l&15), k = kt*64+ks*32+(l>>4)*8+e.
// A wave's B-frag load is then ONE fully-coalesced global_load_dwordx4.
__global__ __launch_bounds__(256) void k_pack_b(const float* __restrict__ w,
                                                __bf16* __restrict__ BF, int N) {
    int tid = blockIdx.x * 256 + threadIdx.x;
    int lane = tid & 63;
    int rest = tid >> 6;
    int N16 = N >> 4;
    int ks = rest & 1;
    int n16 = (rest >> 1) % N16;
    int kt = (rest >> 1) / N16;
    if (kt >= NKT) return;
    int col = n16 * 16 + (lane & 15);
    int k0 = kt * 64 + ks * 32 + (lane >> 4) * 8;
    bf16x8 o;
#pragma unroll
    for (int e = 0; e < 8; ++e) o[e] = (__bf16)w[(size_t)(k0 + e) * N + col];
    *(bf16x8*)(BF + (size_t)tid * 8) = o;
}

// ======== 128x256 bf16 MFMA GEMM, BK=64, B direct from L2 (no B-LDS) ========
// A-only LDS ring-3 (48KB), XOR-swizzled (chunk ^= row&7).  Per K-step:
// 16 ds_read(A-frags), 32 MFMA, load bfv[0..3](t+1), 32 MFMA, load bfv[4..7],
// 4 gload_lds A(t+2), vmcnt(12) [drains A(t+1) only], ONE barrier.
// vmcnt count is reorder-proof: all 12 intra-iteration vmem issues are newer
// than A(t+1) regardless of compiler ordering (pinned by barrier fences).
template <typename OutT>
__global__ __launch_bounds__(256, 2) void gemm_bl(const __bf16* __restrict__ A,
                                                  const __bf16* __restrict__ BF,
                                                  const float* __restrict__ bias,
                                                  OutT* __restrict__ C, int N) {
    __shared__ __align__(1024) char lds[49152];
    const int tid = threadIdx.x;
    const int w = tid >> 6, lane = tid & 63;
    const int l15 = lane & 15, l16 = lane >> 4;
    const int K = KDIM;
    const int N16 = N >> 4;
    const long ktstride = (long)N16 * 1024;   // elems per kt in BF

    // XCD-aware block swizzle (grid % 8 == 0 for both our grids)
    const int nbx = N >> 8;
    const int cpx = gridDim.x >> 3;
    const int bid = blockIdx.x;
    const int swz = (bid & 7) * cpx + (bid >> 3);
    const int brow = swz / nbx, bcol = swz % nbx;
    const long arow0 = (long)brow * 128;
    const int  ncol0 = bcol * 256;

    // ---- A staging: linear LDS dest, pre-swizzled global source ----
    // dest o = slot*16K + j*4096 + w*1024 + lane*16 -> row = j*32+w*8+(lane>>3),
    // chunk' = lane&7; source chunk = chunk' ^ (row&7) = (lane&7)^(lane>>3).
    const __bf16* Asrc = A + (arow0 + w * 8 + (lane >> 3)) * K
                           + (((lane & 7) ^ (lane >> 3)) * 8);
    auto stageA = [&](int slot, int kt) {
#pragma unroll
        for (int j = 0; j < 4; ++j)
            gload_lds16(Asrc + (long)(j * 32) * K + (long)kt * 64,
                        lds + slot * 16384 + j * 4096 + w * 1024 + lane * 16);
    };

    // ---- A-frag read offsets (swizzled): row = mf*16+l15, chunk=(ks*4+l16)^(l15&7)
    const int cA0 = l15 * 128 + (((0 * 4 + l16) ^ (l15 & 7)) * 16);
    const int cA1 = l15 * 128 + (((1 * 4 + l16) ^ (l15 & 7)) * 16);

    // ---- B fragment base: wave w covers n16 = (ncol0>>4) + w*4 + n ----
    const __bf16* bbase = BF + (size_t)lane * 8 + ((long)(ncol0 >> 4) + w * 4) * 1024;

    f32x4 acc[8][4] = {};
    bf16x8 bfv[8];

#define LOADB(KT, HALF) do { \
    _Pragma("unroll") for (int n = 0; n < 4; ++n) \
        bfv[(HALF) * 4 + n] = *(const bf16x8*)(bbase + (long)(KT) * ktstride + n * 1024 + (HALF) * 512); \
} while (0)

#define VMW12 asm volatile("s_waitcnt vmcnt(12)" ::: "memory")
#define VMW8  asm volatile("s_waitcnt vmcnt(8)"  ::: "memory")

#define KSTEP(SLOT, BKT, AKT, VMW, DOBAR) do { \
    bf16x8 af[16]; \
    _Pragma("unroll") for (int mf = 0; mf < 8; ++mf) \
        af[mf] = *(const bf16x8*)(lds + (SLOT) * 16384 + mf * 2048 + cA0); \
    _Pragma("unroll") for (int mf = 0; mf < 8; ++mf) \
        af[8 + mf] = *(const bf16x8*)(lds + (SLOT) * 16384 + mf * 2048 + cA1); \
    __builtin_amdgcn_s_setprio(1); \
    _Pragma("unroll") for (int mf = 0; mf < 8; ++mf) \
        _Pragma("unroll") for (int n = 0; n < 4; ++n) \
            acc[mf][n] = __builtin_amdgcn_mfma_f32_16x16x32_bf16(af[mf], bfv[n], acc[mf][n], 0, 0, 0); \
    __builtin_amdgcn_s_setprio(0); \
    if ((BKT) >= 0) LOADB(BKT, 0); \
    __builtin_amdgcn_s_setprio(1); \
    _Pragma("unroll") for (int mf = 0; mf < 8; ++mf) \
        _Pragma("unroll") for (int n = 0; n < 4; ++n) \
            acc[mf][n] = __builtin_amdgcn_mfma_f32_16x16x32_bf16(af[8 + mf], bfv[4 + n], acc[mf][n], 0, 0, 0); \
    __builtin_amdgcn_s_setprio(0); \
    if ((BKT) >= 0) LOADB(BKT, 1); \
    if ((AKT) >= 0) stageA((AKT) % 3, (AKT)); \
    VMW; \
    if (DOBAR) { __builtin_amdgcn_s_barrier(); __builtin_amdgcn_sched_barrier(0); } \
} while (0)

    // ---- prologue: A(0), B(0), drain, A(1) in flight ----
    stageA(0, 0);
    LOADB(0, 0); LOADB(0, 1);
    asm volatile("s_waitcnt vmcnt(0)" ::: "memory");
    stageA(1, 1);
    __builtin_amdgcn_s_barrier();
    __builtin_amdgcn_sched_barrier(0);

    // ---- main: t=0..8 (3x3), then peel 9,10,11 ----
    for (int t = 0; t < 9; t += 3) {
        KSTEP(0, t + 1, t + 2, VMW12, 1);
        KSTEP(1, t + 2, t + 3, VMW12, 1);
        KSTEP(2, t + 3, t + 4, VMW12, 1);
    }
    KSTEP(0, 10, 11, VMW12, 1);
    KSTEP(1, 11, -1, VMW8, 1);
    KSTEP(2, -1, -1, , 0);
#undef KSTEP
#undef LOADB
#undef VMW12
#undef VMW8

    // ---- C write: row = arow0 + mf*16 + l16*4 + j, col = ncol0 + w*64 + n*16 + l15
#pragma unroll
    for (int mf = 0; mf < 8; ++mf) {
        const int row = (int)arow0 + mf * 16 + l16 * 4;
#pragma unroll
        for (int n = 0; n < 4; ++n) {
            const int col = ncol0 + w * 64 + n * 16 + l15;
            const float bv = bias[col];
#pragma unroll
            for (int j = 0; j < 4; ++j) {
                C[(long)(row + j) * N + col] = (OutT)(acc[mf][n][j] + bv);
            }
        }
    }
}

// ---------------- per-token 12x12 head attention ----------------
#define HPITCH 200
__global__ __launch_bounds__(256) void k_attn(const __bf16* __restrict__ qkv,
                                              __bf16* __restrict__ out) {
    __shared__ __bf16 rows[4][12 * HPITCH];
    __shared__ float wts[4][144];
    const int w = threadIdx.x >> 6, lane = threadIdx.x & 63;
    const long token = (long)blockIdx.x * 4 + w;
    const __bf16* rp = qkv + token * QKVN;
    __bf16* row = rows[w];
    float* wt  = wts[w];

#pragma unroll
    for (int i = 0; i < 4; i++) {
        int c = i * 64 + lane;
        int h = c / 24;
        *(bf16x8*)(row + h * HPITCH + (c * 8 - h * 192)) = *(const bf16x8*)(rp + c * 8);
    }
    if (lane < 32) {
        int c = 256 + lane;
        int h = c / 24;
        *(bf16x8*)(row + h * HPITCH + (c * 8 - h * 192)) = *(const bf16x8*)(rp + c * 8);
    }
    __syncthreads();

    for (int p = lane; p < 144; p += 64) {
        int h = p / 12, g = p - h * 12;
        const __bf16* qp = row + h * HPITCH;
        const __bf16* kp = row + g * HPITCH + 64;
        float s = 0.f;
#pragma unroll
        for (int d = 0; d < 64; d += 8) {
            bf16x8 qv = *(const bf16x8*)(qp + d);
            bf16x8 kv = *(const bf16x8*)(kp + d);
#pragma unroll
            for (int j = 0; j < 8; j++) s += (float)qv[j] * (float)kv[j];
        }
        wt[p] = s * QK_SCALE;
    }
    __syncthreads();

    if (lane < 12) {
        float s[12];
#pragma unroll
        for (int g = 0; g < 12; g++) s[g] = wt[lane * 12 + g];
        float m = s[0];
#pragma unroll
        for (int g = 1; g < 12; g++) m = fmaxf(m, s[g]);
        float sum = 0.f;
#pragma unroll
        for (int g = 0; g < 12; g++) { s[g] = __expf(s[g] - m); sum += s[g]; }
        float inv = 1.0f / sum;
#pragma unroll
        for (int g = 0; g < 12; g++) wt[lane * 12 + g] = s[g] * inv;
    }
    __syncthreads();

    float vr[12];
#pragma unroll
    for (int g = 0; g < 12; g++) vr[g] = (float)row[g * HPITCH + 128 + lane];
#pragma unroll
    for (int h = 0; h < 12; h++) {
        float a = 0.f;
#pragma unroll
        for (int g = 0; g < 12; g++) a += wt[h * 12 + g] * vr[g];
        out[token * EMBED + h * 64 + lane] = (__bf16)a;
    }
}

extern "C" void kernel_launch(void* const* d_in, const int* in_sizes, int n_in,
                              void* d_out, int out_size, void* d_ws, size_t ws_size,
                              hipStream_t stream) {
    const float* x     = (const float*)d_in[0];
    const float* w_qkv = (const float*)d_in[1];
    const float* b_qkv = (const float*)d_in[2];
    const float* w_o   = (const float*)d_in[3];
    const float* b_o   = (const float*)d_in[4];
    float* out = (float*)d_out;

    char* ws = (char*)d_ws;
    size_t off = 0;
    auto take = [&](size_t bytes) {
        char* p = ws + off;
        off += (bytes + 255) & ~(size_t)255;
        return p;
    };
    __bf16* wqkvp = (__bf16*)take((size_t)QKVN * KDIM * 2);   // packed B for GEMM1
    __bf16* wop   = (__bf16*)take((size_t)EMBED * KDIM * 2);  // packed B for GEMM2
    __bf16* xb    = (__bf16*)take((size_t)TOKENS * EMBED * 2);
    __bf16* qkvb  = (__bf16*)take((size_t)TOKENS * QKVN * 2);
    __bf16* attno = xb;  // x_bf16 dead after GEMM1; reuse

    int n4 = TOKENS * EMBED / 4;
    k_cvt_bf16<<<2048, 256, 0, stream>>>((const float4*)x, (bf16x4*)xb, n4);

    // pack weights into fragment order
    k_pack_b<<<(NKT * (QKVN / 16) * 2 * 64) / 256, 256, 0, stream>>>(w_qkv, wqkvp, QKVN);
    k_pack_b<<<(NKT * (EMBED / 16) * 2 * 64) / 256, 256, 0, stream>>>(w_o, wop, EMBED);

    // GEMM1: qkv = x @ w_qkv + b_qkv -> bf16   (2304 wg, %8==0)
    gemm_bl<__bf16><<<(TOKENS / 128) * (QKVN / 256), 256, 0, stream>>>(
        xb, wqkvp, b_qkv, qkvb, QKVN);

    k_attn<<<TOKENS / 4, 256, 0, stream>>>(qkvb, attno);

    // GEMM2: out = attn_out @ w_o + b_o -> f32  (768 wg, %8==0)
    gemm_bl<float><<<(TOKENS / 128) * (EMBED / 256), 256, 0, stream>>>(
        attno, wop, b_o, out, EMBED);
}